// Round 9
// baseline (138.774 us; speedup 1.0000x reference)
//
#include <hip/hip_runtime.h>
#include <math.h>

// ---------------------------------------------------------------------------
// IrrepsToHessian, round 9.
//
// R8 post-mortem: 3 kernels (mq, cart, sym) all below the 43us harness-fill
// cutoff; ~50us harness floor; remaining waste = the mq->cart launch barrier
// (full serialization + Mq HBM round-trip between kernels).
//
// R9: tp_kernel fuses mq+cart. Per wave: compute Mq (phases A+B) -> store to
// ws -> s_waitcnt vmcnt(0) (own stores in L2; vector L1 is write-through) ->
// read back via const-__restrict__ alias on the SCALAR pipe (s_load,
// SGPR-operand v_fmac). No grid sync: each wave reads only its own slice.
// Mq stays in the writer XCD's L2. LDS overlaid: A/B arena (wq tables, sT,
// sMq, 40.6KB) reused in phase C for X2T+sOut (46.6KB) -> 3 blocks/CU; blocks
// in different phases overlap LDS-heavy and VALU-heavy work.
// ---------------------------------------------------------------------------

#define NPATH 15

// ======================= compile-time Wigner machinery =====================
constexpr double cfact(int n){ double r = 1.0; for (int i = 2; i <= n; ++i) r *= (double)i; return r; }
constexpr double csqrt(double x){
  if (x <= 0.0) return 0.0;
  double g = x < 1.0 ? 1.0 : x;
  for (int i = 0; i < 64; ++i) g = 0.5*(g + x/g);
  return g;
}

constexpr double ccg(int j1,int m1,int j2,int m2,int j3,int m3){
  if (m3 != m1 + m2) return 0.0;
  int vmin = -j1 + j2 + m3;
  if (-j1 + m1 > vmin) vmin = -j1 + m1;
  if (0 > vmin) vmin = 0;
  int vmax = j2 + j3 + m1;
  if (j3 - j1 + j2 < vmax) vmax = j3 - j1 + j2;
  if (j3 + m3 < vmax) vmax = j3 + m3;
  double C = csqrt((2.0*j3+1.0)*cfact(j3+j1-j2)*cfact(j3-j1+j2)*cfact(j1+j2-j3)
                   *cfact(j3+m3)*cfact(j3-m3)
                   /(cfact(j1+j2+j3+1)*cfact(j1-m1)*cfact(j1+m1)*cfact(j2-m2)*cfact(j2+m2)));
  double S = 0.0;
  for (int v = vmin; v <= vmax; ++v){
    double term = cfact(j2+j3+m1-v)*cfact(j1-m1+v)
                /(cfact(v)*cfact(j3-j1+j2-v)*cfact(j3+m3-v)*cfact(v+j1-j2-m3));
    S += ((v + j2 + m2) & 1) ? -term : term;
  }
  return C * S;
}

struct QM { double re[5][5]; double im[5][5]; };
constexpr QM cbuild_q(int l){
  QM q{};
  double s = 1.0 / csqrt(2.0);
  for (int m = -l; m < 0; ++m){
    q.re[l+m][l-m] = s;
    q.im[l+m][l+m] = -s;
  }
  q.re[l][l] = 1.0;
  for (int m = 1; m <= l; ++m){
    double sg = (m & 1) ? -1.0 : 1.0;
    q.re[l+m][l+m] = sg * s;
    q.im[l+m][l-m] = sg * s;
  }
  if (l == 1){           // * (-i): (a+bi) -> (b, -a)
    for (int r = 0; r < 5; ++r)
      for (int c = 0; c < 5; ++c){
        double a = q.re[r][c], b = q.im[r][c];
        q.re[r][c] = b; q.im[r][c] = -a;
      }
  } else if (l == 2){    // * (-1)
    for (int r = 0; r < 5; ++r)
      for (int c = 0; c < 5; ++c){ q.re[r][c] = -q.re[r][c]; q.im[r][c] = -q.im[r][c]; }
  }
  return q;
}

struct CRP { double v[125]; };   // normalized real w3j, [(i*d2+j)*d3+m]
constexpr CRP make_cr(int l1, int l2, int l3){
  QM q1 = cbuild_q(l1), q2 = cbuild_q(l2), q3 = cbuild_q(l3);
  const int d1 = 2*l1+1, d2 = 2*l2+1, d3 = 2*l3+1;
  double CG[125] = {};
  for (int i = 0; i < d1; ++i)
    for (int k = 0; k < d2; ++k)
      for (int m = 0; m < d3; ++m)
        CG[(i*5 + k)*5 + m] = ccg(l1, i-l1, l2, k-l2, l3, m-l3);
  CRP o{};
  for (int j = 0; j < d1; ++j)
    for (int l = 0; l < d2; ++l)
      for (int n = 0; n < d3; ++n){
        double acc = 0.0;
        for (int i = 0; i < d1; ++i)
          for (int k = 0; k < d2; ++k)
            for (int m = 0; m < d3; ++m){
              double c = CG[(i*5 + k)*5 + m];
              if (c == 0.0) continue;
              double are = q1.re[i][j], aim = q1.im[i][j];
              double bre = q2.re[k][l], bim = q2.im[k][l];
              double tre = are*bre - aim*bim;
              double tim = are*bim + aim*bre;
              double cre = q3.re[m][n], cim = q3.im[m][n];
              acc += (tre*cre + tim*cim) * c;   // Re( q1 q2 conj(q3) CG )
            }
        o.v[(j*d2 + l)*d3 + n] = acc;
      }
  double s2 = 0.0;
  for (int e = 0; e < d1*d2*d3; ++e) s2 += o.v[e]*o.v[e];
  double inv = 1.0 / csqrt(s2);
  for (int e = 0; e < d1*d2*d3; ++e) o.v[e] *= inv;
  return o;
}

// one constexpr variable per path -> each evaluation has its own step budget
constexpr CRP CR0  = make_cr(0,0,0);
constexpr CRP CR1  = make_cr(1,1,0);
constexpr CRP CR2  = make_cr(2,2,0);
constexpr CRP CR3  = make_cr(0,1,1);
constexpr CRP CR4  = make_cr(1,0,1);
constexpr CRP CR5  = make_cr(1,1,1);
constexpr CRP CR6  = make_cr(1,2,1);
constexpr CRP CR7  = make_cr(2,1,1);
constexpr CRP CR8  = make_cr(2,2,1);
constexpr CRP CR9  = make_cr(0,2,2);
constexpr CRP CR10 = make_cr(2,0,2);
constexpr CRP CR11 = make_cr(1,1,2);
constexpr CRP CR12 = make_cr(1,2,2);
constexpr CRP CR13 = make_cr(2,1,2);
constexpr CRP CR14 = make_cr(2,2,2);

struct QCT { double v[81]; };    // QCART[lm][i*3+j]
constexpr QCT make_qc(){
  QCT q{};
  for (int lm = 0; lm < 9; ++lm){
    int l = (lm == 0) ? 0 : ((lm < 4) ? 1 : 2);
    int m = lm - l*l;
    const CRP& cr = (l == 0) ? CR1 : ((l == 1) ? CR5 : CR11);  // paths (1,1,l)
    double sc = csqrt(2.0*l + 1.0);
    for (int r = 0; r < 9; ++r)
      q.v[lm*9 + r] = cr.v[r*(2*l+1) + m] * sc;
  }
  return q;
}
constexpr QCT QCt = make_qc();

// wq layout: 189 rows, split b8 (a<8) + b1 (a==8)
struct WQT { float b8[189*8]; float b1[189]; };
constexpr WQT make_wq(){
  WQT t{};
  const CRP* crs[NPATH] = {&CR0,&CR1,&CR2,&CR3,&CR4,&CR5,&CR6,&CR7,&CR8,&CR9,
                           &CR10,&CR11,&CR12,&CR13,&CR14};
  const int L1[NPATH]   = {0,1,2,0,1,1,1,2,2,0,2,1,1,2,2};
  const int L2[NPATH]   = {0,1,2,1,0,1,2,1,2,2,0,1,2,1,2};
  const int LO[NPATH]   = {0,0,0,1,1,1,1,1,1,2,2,2,2,2,2};
  const int PROW[NPATH] = {0,1,10,35,38,41,50,65,80,105,110,115,124,139,164};
  const double AL[3] = { csqrt(1.0/768.0), csqrt(3.0/1536.0), csqrt(5.0/1536.0) };
  for (int p = 0; p < NPATH; ++p){
    const int d1 = 2*L1[p]+1, d2 = 2*L2[p]+1, d3 = 2*LO[p]+1, lo = LO[p];
    for (int i = 0; i < d1; ++i)
      for (int j = 0; j < d2; ++j)
        for (int a = 0; a < 9; ++a){
          double acc = 0.0;
          for (int m = 0; m < d3; ++m)
            acc += crs[p]->v[(i*d2 + j)*d3 + m] * QCt.v[(lo*lo + m)*9 + a];
          double val = AL[lo] * acc;
          int row = PROW[p] + i*d2 + j;
          if (a < 8) t.b8[row*8 + a] = (float)val;
          else       t.b1[row]       = (float)val;
        }
  }
  return t;
}
__constant__ WQT cWQ = make_wq();

// ======================= runtime tables ====================================
__constant__ int cP_L1[NPATH]   = {0,1,2,0,1,1,1,2,2,0,2,1,1,2,2};
__constant__ int cC2P[51] = {0, 1,1,1, 2,2,2,2,2, 3, 4,4,4, 5,5,5, 6,6,6,
                             7,7,7,7,7, 8,8,8,8,8, 9, 10,10,10,10,10,
                             11,11,11, 12,12,12, 13,13,13,13,13, 14,14,14,14,14};
__constant__ int cC2I[51] = {0, 0,1,2, 0,1,2,3,4, 0, 0,1,2, 0,1,2, 0,1,2,
                             0,1,2,3,4, 0,1,2,3,4, 0, 0,1,2,3,4,
                             0,1,2, 0,1,2, 0,1,2,3,4, 0,1,2,3,4};

#define MQ_STRIDE 1296

// LDS arena (floats), phase A/B layout:
//   [0,1512)        sB8          [1512,1704) sB1 (189 used)
//   [1704,4968)     sT   (4 x 816)
//   [4968,10152)    sMq  (4 x 1296)
// phase C layout (reuses [0,10152)):
//   [0,9360)        sX2T (144 x 65)
//   [9360,11664)    sOut (4 x 576)
//   [11664,11728)   sCol (64 ints)   -- outside both arenas, loaded early
#define L_B8   0
#define L_B1   1512
#define L_T    1704
#define L_MQ   4968
#define L_X2   0
#define L_OUT  9360
#define L_COL  11664
#define L_TOT  11728   // 46912 B -> 3 blocks/CU

// ACCP: one path's contribution to acc[9]
#define ACCP(TOFF_, PROW_, D1_)                                              \
  { _Pragma("unroll")                                                        \
    for (int i = 0; i < (D1_); ++i){                                         \
      float tv = pT[((TOFF_) + i) * 16 + v];                                 \
      int row = (PROW_) + i * D2 + j;                                        \
      const float4 m0 = *(const float4*)&sB8[row * 8];                       \
      const float4 m1 = *(const float4*)&sB8[row * 8 + 4];                   \
      const float  m8 = sB1[row];                                            \
      acc[0] += tv*m0.x; acc[1] += tv*m0.y; acc[2] += tv*m0.z;               \
      acc[3] += tv*m0.w; acc[4] += tv*m1.x; acc[5] += tv*m1.y;               \
      acc[6] += tv*m1.z; acc[7] += tv*m1.w; acc[8] += tv*m8;                 \
    } }

// ---------------------------------------------------------------------------
// tp_kernel: fused mq + cart. 256 thr = 4 waves, wave per row-block.
// ---------------------------------------------------------------------------
__global__ __launch_bounds__(256) void tp_kernel(
    const float* __restrict__ feats,    // (4096, 144)
    const int*   __restrict__ layout,   // (E, 2)
    const float* __restrict__ tpw,      // (15, 16, 16)
    float*       __restrict__ mqw,      // ws: Mq write alias
    const float* __restrict__ mqr,      // ws: Mq read alias (scalar path)
    float*       __restrict__ out)      // (E, 9) unsymmetrized cart
{
  __shared__ __align__(16) float lds[L_TOT];
  float* sB8 = lds + L_B8;
  float* sB1 = lds + L_B1;
  int*   sCol = (int*)(lds + L_COL);
  const int tid  = threadIdx.x;
  const int wave = tid >> 6;
  const int lane = tid & 63;
  const int rwBase = blockIdx.x * 4;        // 4 row-blocks, same config
  const int rw = rwBase + wave;

  // stage wq tables + column ids (sCol region never overlaps A/B arena)
  for (int o = tid; o < 1512; o += 256) sB8[o] = cWQ.b8[o];
  if (tid < 189) sB1[tid] = cWQ.b1[tid];
  if (tid < 64)  sCol[tid] = layout[2 * ((size_t)rwBase * 64 + tid) + 1];

  int rowNode = layout[2 * (rw * 64)];
  rowNode = __builtin_amdgcn_readfirstlane(rowNode);
  const float* __restrict__ x1 = feats + (size_t)rowNode * 144;

  // ---- Phase A: t[k][v] (wave-local region) ----
  float* pT = lds + L_T + wave * 816;
  {
    const int v  = lane & 15;
    const int cq = lane >> 4;
    for (int it = 0; it < 13; ++it){
      int c = cq + it * 4;
      if (c < 51){
        int p = cC2P[c], i = cC2I[c];
        int l1 = cP_L1[p];
        int st = 2*l1 + 1;
        int loff = (l1 == 0) ? 0 : ((l1 == 1) ? 16 : 64);
        const float* xb = x1 + loff + i;
        const float* wb = tpw + p * 256 + v;
        float s = 0.f;
        #pragma unroll
        for (int u = 0; u < 16; ++u) s += xb[u * st] * wb[u * 16];
        pT[c * 16 + v] = s;
      }
    }
  }

  __syncthreads();   // sB8/sB1 staged before Phase B

  // ---- Phase B: Mq[c][a] c-major into wave-local LDS ----
  float* pM = lds + L_MQ + wave * 1296;
  for (int rnd = 0; rnd < 3; ++rnd){
    int c = lane + rnd * 64;
    if (c >= 144) break;
    float acc[9];
    #pragma unroll
    for (int a = 0; a < 9; ++a) acc[a] = 0.f;
    if (c < 16){                    // l2 = 0 : paths 0,4,10
      const int v = c, j = 0;
      const int D2 = 1;
      ACCP(0,  0,   1)
      ACCP(10, 38,  3)
      ACCP(30, 110, 5)
    } else if (c < 64){             // l2 = 1 : paths 1,3,5,7,11,13
      const int v = (c - 16) / 3, j = (c - 16) % 3;
      const int D2 = 3;
      ACCP(1,  1,   3)
      ACCP(9,  35,  1)
      ACCP(13, 41,  3)
      ACCP(19, 65,  5)
      ACCP(35, 115, 3)
      ACCP(41, 139, 5)
    } else {                        // l2 = 2 : paths 2,6,8,9,12,14
      const int v = (c - 64) / 5, j = (c - 64) % 5;
      const int D2 = 5;
      ACCP(4,  10,  5)
      ACCP(16, 50,  3)
      ACCP(24, 80,  5)
      ACCP(29, 105, 1)
      ACCP(38, 124, 3)
      ACCP(46, 164, 5)
    }
    #pragma unroll
    for (int a = 0; a < 9; ++a) pM[c * 9 + a] = acc[a];
  }

  // store this wave's Mq to global (coalesced b128); wave-local LDS order
  {
    float* dst = mqw + (size_t)rw * MQ_STRIDE;
    #pragma unroll
    for (int r = 0; r < 6; ++r){
      int idx = lane + r * 64;               // float4 index 0..323
      if (idx < 324){
        float4 vv = *(const float4*)(pM + idx * 4);
        *(float4*)(dst + idx * 4) = vv;
      }
    }
  }
  // drain own stores to L2 before the scalar-path read-back; also a compiler
  // barrier so the restrict'd mqr loads cannot be hoisted above the stores.
  __asm__ __volatile__("s_waitcnt vmcnt(0)" ::: "memory");

  __syncthreads();   // all waves done with sT/sMq/sB arenas -> safe to reuse

  // ---- Phase C staging: X2 transposed, column-major [c][j], pad 65 ----
  {
    float* sX2 = lds + L_X2;
    #pragma unroll
    for (int k = 0; k < 9; ++k){
      int q = k * 256 + tid;                 // 0..2303 float4 tasks
      int j = q / 36, c4 = q - j * 36;
      const float4 xv = *(const float4*)(feats + (size_t)sCol[j] * 144 + c4 * 4);
      int c0 = c4 * 4;
      sX2[(c0+0)*65 + j] = xv.x;
      sX2[(c0+1)*65 + j] = xv.y;
      sX2[(c0+2)*65 + j] = xv.z;
      sX2[(c0+3)*65 + j] = xv.w;
    }
  }
  __syncthreads();

  // ---- Phase C: acc[9] = sum_c x2T[c][lane] * Mq[c][a] via s_load ----
  const float* mq = mqr + (size_t)rw * MQ_STRIDE;   // uniform -> SGPR base
  const float* sX2 = lds + L_X2;

  float acc[9];
  #pragma unroll
  for (int a = 0; a < 9; ++a) acc[a] = 0.f;

  #pragma unroll 8
  for (int c = 0; c < 144; ++c){
    float x = sX2[c * 65 + lane];
    #pragma unroll
    for (int a = 0; a < 9; ++a) acc[a] += x * mq[c * 9 + a];
  }

  // coalesced store via LDS staging (wave-local)
  {
    float* pO = lds + L_OUT + wave * 576;
    #pragma unroll
    for (int a = 0; a < 9; ++a) pO[lane * 9 + a] = acc[a];
    float* ob = out + (size_t)rw * 576;
    #pragma unroll
    for (int r = 0; r < 3; ++r){
      int idx = lane + r * 64;               // float4 index 0..143
      if (idx < 144){
        float4 vv = *(const float4*)(pO + idx * 4);
        *(float4*)(ob + idx * 4) = vv;
      }
    }
  }
}

// ---------------------------------------------------------------------------
// fallback: fused LDS-broadcast kernel (used only if ws is too small)
// ---------------------------------------------------------------------------
__global__ __launch_bounds__(256, 4) void fused_kernel(
    const float* __restrict__ feats,
    const int*   __restrict__ layout,
    const float* __restrict__ tpw,
    float*       __restrict__ out)
{
  __shared__ __align__(16) float sB8[189 * 8];
  __shared__ float sB1[192];
  __shared__ __align__(16) float sT[4][816];
  __shared__ __align__(16) float sMqT[4][1296];
  const int tid  = threadIdx.x;
  const int wave = tid >> 6;
  const int lane = tid & 63;

  for (int o = tid; o < 1512; o += 256) sB8[o] = cWQ.b8[o];
  if (tid < 189) sB1[tid] = cWQ.b1[tid];

  const int rw = blockIdx.x * 4 + wave;
  const int e0 = rw * 64;
  int rowNode = layout[2 * e0];
  rowNode = __builtin_amdgcn_readfirstlane(rowNode);
  const float* __restrict__ x1 = feats + (size_t)rowNode * 144;

  float* __restrict__ pT = sT[wave];
  {
    const int v  = lane & 15;
    const int cq = lane >> 4;
    for (int it = 0; it < 13; ++it){
      int c = cq + it * 4;
      if (c < 51){
        int p = cC2P[c], i = cC2I[c];
        int l1 = cP_L1[p];
        int st = 2*l1 + 1;
        int loff = (l1 == 0) ? 0 : ((l1 == 1) ? 16 : 64);
        const float* xb = x1 + loff + i;
        const float* wb = tpw + p * 256 + v;
        float s = 0.f;
        #pragma unroll
        for (int u = 0; u < 16; ++u) s += xb[u * st] * wb[u * 16];
        pT[c * 16 + v] = s;
      }
    }
  }
  __syncthreads();

  float* __restrict__ pM = sMqT[wave];
  for (int rnd = 0; rnd < 3; ++rnd){
    int c = lane + rnd * 64;
    if (c >= 144) break;
    float acc[9];
    #pragma unroll
    for (int a = 0; a < 9; ++a) acc[a] = 0.f;
    if (c < 16){
      const int v = c, j = 0;
      const int D2 = 1;
      ACCP(0,  0,   1)
      ACCP(10, 38,  3)
      ACCP(30, 110, 5)
    } else if (c < 64){
      const int v = (c - 16) / 3, j = (c - 16) % 3;
      const int D2 = 3;
      ACCP(1,  1,   3)
      ACCP(9,  35,  1)
      ACCP(13, 41,  3)
      ACCP(19, 65,  5)
      ACCP(35, 115, 3)
      ACCP(41, 139, 5)
    } else {
      const int v = (c - 64) / 5, j = (c - 64) % 5;
      const int D2 = 5;
      ACCP(4,  10,  5)
      ACCP(16, 50,  3)
      ACCP(24, 80,  5)
      ACCP(29, 105, 1)
      ACCP(38, 124, 3)
      ACCP(46, 164, 5)
    }
    #pragma unroll
    for (int a = 0; a < 9; ++a) pM[a * 144 + c] = acc[a];
  }

  const size_t e = (size_t)e0 + lane;
  const int col = layout[2 * e + 1];
  const float* __restrict__ x2 = feats + (size_t)col * 144;

  float acc[9];
  #pragma unroll
  for (int a = 0; a < 9; ++a) acc[a] = 0.f;

  for (int cc = 0; cc < 36; ++cc){
    const float4 x = *(const float4*)(x2 + cc * 4);
    const float* mb = pM + cc * 4;
    #pragma unroll
    for (int a = 0; a < 9; ++a){
      float4 mv = *(const float4*)(mb + a * 144);
      acc[a] += x.x*mv.x + x.y*mv.y + x.z*mv.z + x.w*mv.w;
    }
  }

  #pragma unroll
  for (int a = 0; a < 9; ++a) pT[lane * 9 + a] = acc[a];
  float* ob = out + (size_t)e0 * 9;
  #pragma unroll
  for (int r = 0; r < 3; ++r){
    int idx = lane + r * 64;
    if (idx < 144){
      float4 vv = *(const float4*)(pT + idx * 4);
      *(float4*)(ob + idx * 4) = vv;
    }
  }
}

// ---------------------------------------------------------------------------
// sym_tiled: 16x16 cell tile-pairs through LDS; fully coalesced; each element
// read+written exactly once. Block = (config b, tile-pair tp), 256 threads.
// ---------------------------------------------------------------------------
__global__ __launch_bounds__(256) void sym_tiled(float* __restrict__ out){
  __shared__ float sA[16 * 145];
  __shared__ float sB[16 * 145];
  const int tid = threadIdx.x;
  const int b  = blockIdx.x / 10;
  const int tp = blockIdx.x - b * 10;
  const int TI[10] = {0,0,0,0,1,1,1,2,2,3};
  const int TJ[10] = {0,1,2,3,1,2,3,2,3,3};
  const int ti = TI[tp], tj = TJ[tp];
  const bool diag = (ti == tj);
  const size_t cfgBase = (size_t)b * 4096 * 9;

  for (int idx = tid; idx < 2304; idx += 256){
    int r = idx / 144, off = idx - r * 144;
    sA[r * 145 + off] = out[cfgBase + ((size_t)(ti*16 + r) * 64 + tj*16) * 9 + off];
  }
  if (!diag){
    for (int idx = tid; idx < 2304; idx += 256){
      int r = idx / 144, off = idx - r * 144;
      sB[r * 145 + off] = out[cfgBase + ((size_t)(tj*16 + r) * 64 + ti*16) * 9 + off];
    }
  }
  __syncthreads();

  const int di = tid >> 4, dj = tid & 15;
  const float* A = sA;
  const float* B = diag ? sA : sB;
  float oa[9], ob[9];
  #pragma unroll
  for (int a = 0; a < 3; ++a)
    #pragma unroll
    for (int d = 0; d < 3; ++d){
      oa[a*3+d] = 0.5f * (A[di*145 + dj*9 + a*3+d] + B[dj*145 + di*9 + d*3+a]);
      if (!diag)
        ob[a*3+d] = 0.5f * (B[di*145 + dj*9 + a*3+d] + A[dj*145 + di*9 + d*3+a]);
    }
  __syncthreads();

  #pragma unroll
  for (int r9 = 0; r9 < 9; ++r9) sA[di*145 + dj*9 + r9] = oa[r9];
  if (!diag){
    #pragma unroll
    for (int r9 = 0; r9 < 9; ++r9) sB[di*145 + dj*9 + r9] = ob[r9];
  }
  __syncthreads();

  for (int idx = tid; idx < 2304; idx += 256){
    int r = idx / 144, off = idx - r * 144;
    out[cfgBase + ((size_t)(ti*16 + r) * 64 + tj*16) * 9 + off] = sA[r * 145 + off];
  }
  if (!diag){
    for (int idx = tid; idx < 2304; idx += 256){
      int r = idx / 144, off = idx - r * 144;
      out[cfgBase + ((size_t)(tj*16 + r) * 64 + ti*16) * 9 + off] = sB[r * 145 + off];
    }
  }
}

// ---------------------------------------------------------------------------
extern "C" void kernel_launch(void* const* d_in, const int* in_sizes, int n_in,
                              void* d_out, int out_size, void* d_ws, size_t ws_size,
                              hipStream_t stream) {
  const float* feats  = (const float*)d_in[0];   // (4096, 144)
  const int*   layout = (const int*)  d_in[1];   // (E, 2)
  const float* tpw    = (const float*)d_in[2];   // (15, 16, 16)
  float* out = (float*)d_out;
  float* ws  = (float*)d_ws;

  const int E = in_sizes[1] / 2;                 // 262144
  const int R = E / 64;                          // 4096 row-blocks
  const int B = E / 4096;                        // 64 configs

  const size_t need = (size_t)R * MQ_STRIDE * sizeof(float);
  if (ws_size >= need){
    tp_kernel<<<R / 4, 256, 0, stream>>>(feats, layout, tpw, ws, ws, out);
  } else {
    fused_kernel<<<R / 4, 256, 0, stream>>>(feats, layout, tpw, out);
  }
  sym_tiled<<<B * 10, 256, 0, stream>>>(out);
}

// Round 10
// 132.051 us; speedup vs baseline: 1.0509x; 1.0509x over previous
//
#include <hip/hip_runtime.h>
#include <math.h>

// ---------------------------------------------------------------------------
// IrrepsToHessian, round 10.
//
// R9 post-mortem: intra-kernel Mq bounce (tp_kernel) regressed to 74us --
// per-wave vmcnt(0) drain with no cross-phase waves to hide it + 47KB arena
// occupancy loss. Reverting to R8's proven mq/cart/sym split (124us).
//
// R10 delta vs R8: packed fp32 math. acc[0..8] -> float2 acc2[4] + acc8 in
// both mq Phase B (ACCP) and cart Phase C, so the compiler can emit
// v_pk_fma_f32 (2 FMA/cyc/lane). Mq scalars pair naturally (s_load SGPR
// pairs in cart, b128 LDS quads in mq). Identical fp32 numerics.
// ---------------------------------------------------------------------------

#define NPATH 15

// ======================= compile-time Wigner machinery =====================
constexpr double cfact(int n){ double r = 1.0; for (int i = 2; i <= n; ++i) r *= (double)i; return r; }
constexpr double csqrt(double x){
  if (x <= 0.0) return 0.0;
  double g = x < 1.0 ? 1.0 : x;
  for (int i = 0; i < 64; ++i) g = 0.5*(g + x/g);
  return g;
}

constexpr double ccg(int j1,int m1,int j2,int m2,int j3,int m3){
  if (m3 != m1 + m2) return 0.0;
  int vmin = -j1 + j2 + m3;
  if (-j1 + m1 > vmin) vmin = -j1 + m1;
  if (0 > vmin) vmin = 0;
  int vmax = j2 + j3 + m1;
  if (j3 - j1 + j2 < vmax) vmax = j3 - j1 + j2;
  if (j3 + m3 < vmax) vmax = j3 + m3;
  double C = csqrt((2.0*j3+1.0)*cfact(j3+j1-j2)*cfact(j3-j1+j2)*cfact(j1+j2-j3)
                   *cfact(j3+m3)*cfact(j3-m3)
                   /(cfact(j1+j2+j3+1)*cfact(j1-m1)*cfact(j1+m1)*cfact(j2-m2)*cfact(j2+m2)));
  double S = 0.0;
  for (int v = vmin; v <= vmax; ++v){
    double term = cfact(j2+j3+m1-v)*cfact(j1-m1+v)
                /(cfact(v)*cfact(j3-j1+j2-v)*cfact(j3+m3-v)*cfact(v+j1-j2-m3));
    S += ((v + j2 + m2) & 1) ? -term : term;
  }
  return C * S;
}

struct QM { double re[5][5]; double im[5][5]; };
constexpr QM cbuild_q(int l){
  QM q{};
  double s = 1.0 / csqrt(2.0);
  for (int m = -l; m < 0; ++m){
    q.re[l+m][l-m] = s;
    q.im[l+m][l+m] = -s;
  }
  q.re[l][l] = 1.0;
  for (int m = 1; m <= l; ++m){
    double sg = (m & 1) ? -1.0 : 1.0;
    q.re[l+m][l+m] = sg * s;
    q.im[l+m][l-m] = sg * s;
  }
  if (l == 1){           // * (-i): (a+bi) -> (b, -a)
    for (int r = 0; r < 5; ++r)
      for (int c = 0; c < 5; ++c){
        double a = q.re[r][c], b = q.im[r][c];
        q.re[r][c] = b; q.im[r][c] = -a;
      }
  } else if (l == 2){    // * (-1)
    for (int r = 0; r < 5; ++r)
      for (int c = 0; c < 5; ++c){ q.re[r][c] = -q.re[r][c]; q.im[r][c] = -q.im[r][c]; }
  }
  return q;
}

struct CRP { double v[125]; };   // normalized real w3j, [(i*d2+j)*d3+m]
constexpr CRP make_cr(int l1, int l2, int l3){
  QM q1 = cbuild_q(l1), q2 = cbuild_q(l2), q3 = cbuild_q(l3);
  const int d1 = 2*l1+1, d2 = 2*l2+1, d3 = 2*l3+1;
  double CG[125] = {};
  for (int i = 0; i < d1; ++i)
    for (int k = 0; k < d2; ++k)
      for (int m = 0; m < d3; ++m)
        CG[(i*5 + k)*5 + m] = ccg(l1, i-l1, l2, k-l2, l3, m-l3);
  CRP o{};
  for (int j = 0; j < d1; ++j)
    for (int l = 0; l < d2; ++l)
      for (int n = 0; n < d3; ++n){
        double acc = 0.0;
        for (int i = 0; i < d1; ++i)
          for (int k = 0; k < d2; ++k)
            for (int m = 0; m < d3; ++m){
              double c = CG[(i*5 + k)*5 + m];
              if (c == 0.0) continue;
              double are = q1.re[i][j], aim = q1.im[i][j];
              double bre = q2.re[k][l], bim = q2.im[k][l];
              double tre = are*bre - aim*bim;
              double tim = are*bim + aim*bre;
              double cre = q3.re[m][n], cim = q3.im[m][n];
              acc += (tre*cre + tim*cim) * c;   // Re( q1 q2 conj(q3) CG )
            }
        o.v[(j*d2 + l)*d3 + n] = acc;
      }
  double s2 = 0.0;
  for (int e = 0; e < d1*d2*d3; ++e) s2 += o.v[e]*o.v[e];
  double inv = 1.0 / csqrt(s2);
  for (int e = 0; e < d1*d2*d3; ++e) o.v[e] *= inv;
  return o;
}

// one constexpr variable per path -> each evaluation has its own step budget
constexpr CRP CR0  = make_cr(0,0,0);
constexpr CRP CR1  = make_cr(1,1,0);
constexpr CRP CR2  = make_cr(2,2,0);
constexpr CRP CR3  = make_cr(0,1,1);
constexpr CRP CR4  = make_cr(1,0,1);
constexpr CRP CR5  = make_cr(1,1,1);
constexpr CRP CR6  = make_cr(1,2,1);
constexpr CRP CR7  = make_cr(2,1,1);
constexpr CRP CR8  = make_cr(2,2,1);
constexpr CRP CR9  = make_cr(0,2,2);
constexpr CRP CR10 = make_cr(2,0,2);
constexpr CRP CR11 = make_cr(1,1,2);
constexpr CRP CR12 = make_cr(1,2,2);
constexpr CRP CR13 = make_cr(2,1,2);
constexpr CRP CR14 = make_cr(2,2,2);

struct QCT { double v[81]; };    // QCART[lm][i*3+j]
constexpr QCT make_qc(){
  QCT q{};
  for (int lm = 0; lm < 9; ++lm){
    int l = (lm == 0) ? 0 : ((lm < 4) ? 1 : 2);
    int m = lm - l*l;
    const CRP& cr = (l == 0) ? CR1 : ((l == 1) ? CR5 : CR11);  // paths (1,1,l)
    double sc = csqrt(2.0*l + 1.0);
    for (int r = 0; r < 9; ++r)
      q.v[lm*9 + r] = cr.v[r*(2*l+1) + m] * sc;
  }
  return q;
}
constexpr QCT QCt = make_qc();

// wq layout: 189 rows, split b8 (a<8) + b1 (a==8)
struct WQT { float b8[189*8]; float b1[189]; };
constexpr WQT make_wq(){
  WQT t{};
  const CRP* crs[NPATH] = {&CR0,&CR1,&CR2,&CR3,&CR4,&CR5,&CR6,&CR7,&CR8,&CR9,
                           &CR10,&CR11,&CR12,&CR13,&CR14};
  const int L1[NPATH]   = {0,1,2,0,1,1,1,2,2,0,2,1,1,2,2};
  const int L2[NPATH]   = {0,1,2,1,0,1,2,1,2,2,0,1,2,1,2};
  const int LO[NPATH]   = {0,0,0,1,1,1,1,1,1,2,2,2,2,2,2};
  const int PROW[NPATH] = {0,1,10,35,38,41,50,65,80,105,110,115,124,139,164};
  const double AL[3] = { csqrt(1.0/768.0), csqrt(3.0/1536.0), csqrt(5.0/1536.0) };
  for (int p = 0; p < NPATH; ++p){
    const int d1 = 2*L1[p]+1, d2 = 2*L2[p]+1, d3 = 2*LO[p]+1, lo = LO[p];
    for (int i = 0; i < d1; ++i)
      for (int j = 0; j < d2; ++j)
        for (int a = 0; a < 9; ++a){
          double acc = 0.0;
          for (int m = 0; m < d3; ++m)
            acc += crs[p]->v[(i*d2 + j)*d3 + m] * QCt.v[(lo*lo + m)*9 + a];
          double val = AL[lo] * acc;
          int row = PROW[p] + i*d2 + j;
          if (a < 8) t.b8[row*8 + a] = (float)val;
          else       t.b1[row]       = (float)val;
        }
  }
  return t;
}
__constant__ WQT cWQ = make_wq();

// ======================= runtime tables ====================================
__constant__ int cP_L1[NPATH]   = {0,1,2,0,1,1,1,2,2,0,2,1,1,2,2};
__constant__ int cC2P[51] = {0, 1,1,1, 2,2,2,2,2, 3, 4,4,4, 5,5,5, 6,6,6,
                             7,7,7,7,7, 8,8,8,8,8, 9, 10,10,10,10,10,
                             11,11,11, 12,12,12, 13,13,13,13,13, 14,14,14,14,14};
__constant__ int cC2I[51] = {0, 0,1,2, 0,1,2,3,4, 0, 0,1,2, 0,1,2, 0,1,2,
                             0,1,2,3,4, 0,1,2,3,4, 0, 0,1,2,3,4,
                             0,1,2, 0,1,2, 0,1,2,3,4, 0,1,2,3,4};

#define MQ_STRIDE 1296

// ACCP: one path's contribution, packed-fp32 form (float2 acc2[4] + acc8)
#define ACCP(TOFF_, PROW_, D1_)                                              \
  { _Pragma("unroll")                                                        \
    for (int i = 0; i < (D1_); ++i){                                         \
      float tv = pT[((TOFF_) + i) * 16 + v];                                 \
      float2 tvv = make_float2(tv, tv);                                      \
      int row = (PROW_) + i * D2 + j;                                        \
      const float2* mp = (const float2*)&sB8[row * 8];                       \
      const float  m8 = sB1[row];                                            \
      acc2[0] += tvv * mp[0]; acc2[1] += tvv * mp[1];                        \
      acc2[2] += tvv * mp[2]; acc2[3] += tvv * mp[3];                        \
      acc8 += tv * m8;                                                       \
    } }

// ---------------------------------------------------------------------------
// mq_kernel: 256 thr = 4 waves; wave computes Mq (c-major [c][a]) for one
// row-block and stores it contiguously to global ws.
// ---------------------------------------------------------------------------
__global__ __launch_bounds__(256, 4) void mq_kernel(
    const float* __restrict__ feats,    // (4096, 144)
    const int*   __restrict__ layout,   // (E, 2)
    const float* __restrict__ tpw,      // (15, 16, 16)
    float*       __restrict__ mqg)      // (4096, 1296) Mq c-major
{
  __shared__ __align__(16) float sB8[189 * 8];      // 6048 B
  __shared__ float sB1[192];                        //  768 B
  __shared__ __align__(16) float sT[4][816];        // 13056 B
  __shared__ __align__(16) float sMq[4][1296];      // 20736 B -> 40.6KB total
  const int tid  = threadIdx.x;
  const int wave = tid >> 6;
  const int lane = tid & 63;

  for (int o = tid; o < 1512; o += 256) sB8[o] = cWQ.b8[o];
  if (tid < 189) sB1[tid] = cWQ.b1[tid];

  const int rw = blockIdx.x * 4 + wave;     // row-block id
  int rowNode = layout[2 * (rw * 64)];
  rowNode = __builtin_amdgcn_readfirstlane(rowNode);
  const float* __restrict__ x1 = feats + (size_t)rowNode * 144;

  // Phase A: t[k][v]  (two accumulators for ILP)
  float* __restrict__ pT = sT[wave];
  {
    const int v  = lane & 15;
    const int cq = lane >> 4;
    for (int it = 0; it < 13; ++it){
      int c = cq + it * 4;
      if (c < 51){
        int p = cC2P[c], i = cC2I[c];
        int l1 = cP_L1[p];
        int st = 2*l1 + 1;
        int loff = (l1 == 0) ? 0 : ((l1 == 1) ? 16 : 64);
        const float* xb = x1 + loff + i;
        const float* wb = tpw + p * 256 + v;
        float s0 = 0.f, s1 = 0.f;
        #pragma unroll
        for (int u = 0; u < 16; u += 2){
          s0 += xb[u * st] * wb[u * 16];
          s1 += xb[(u+1) * st] * wb[(u+1) * 16];
        }
        pT[c * 16 + v] = s0 + s1;
      }
    }
  }

  __syncthreads();   // sB8/sB1 staged; Phase A done

  // Phase B: Mq[c][a], c-major, packed fp32
  float* __restrict__ pM = sMq[wave];
  for (int rnd = 0; rnd < 3; ++rnd){
    int c = lane + rnd * 64;
    if (c >= 144) break;
    float2 acc2[4];
    float acc8 = 0.f;
    #pragma unroll
    for (int k = 0; k < 4; ++k) acc2[k] = make_float2(0.f, 0.f);
    if (c < 16){                    // l2 = 0 : paths 0,4,10
      const int v = c, j = 0;
      const int D2 = 1;
      ACCP(0,  0,   1)
      ACCP(10, 38,  3)
      ACCP(30, 110, 5)
    } else if (c < 64){             // l2 = 1 : paths 1,3,5,7,11,13
      const int v = (c - 16) / 3, j = (c - 16) % 3;
      const int D2 = 3;
      ACCP(1,  1,   3)
      ACCP(9,  35,  1)
      ACCP(13, 41,  3)
      ACCP(19, 65,  5)
      ACCP(35, 115, 3)
      ACCP(41, 139, 5)
    } else {                        // l2 = 2 : paths 2,6,8,9,12,14
      const int v = (c - 64) / 5, j = (c - 64) % 5;
      const int D2 = 5;
      ACCP(4,  10,  5)
      ACCP(16, 50,  3)
      ACCP(24, 80,  5)
      ACCP(29, 105, 1)
      ACCP(38, 124, 3)
      ACCP(46, 164, 5)
    }
    #pragma unroll
    for (int k = 0; k < 4; ++k){
      pM[c * 9 + 2*k]     = acc2[k].x;
      pM[c * 9 + 2*k + 1] = acc2[k].y;
    }
    pM[c * 9 + 8] = acc8;
  }
  // wave-local LDS order: compiler's lgkmcnt before the reads below suffices

  // store Mq contiguously (coalesced b128)
  float* __restrict__ dst = mqg + (size_t)rw * MQ_STRIDE;
  #pragma unroll
  for (int r = 0; r < 6; ++r){
    int idx = lane + r * 64;                 // float4 index 0..323
    if (idx < 324){
      float4 vv = *(const float4*)(pM + idx * 4);
      *(float4*)(dst + idx * 4) = vv;
    }
  }
}

// ---------------------------------------------------------------------------
// cart_kernel: block = 4 row-blocks of ONE config (share the 64 columns).
// X2 staged transposed in LDS (pad 65 -> conflict-free b32 reads); Mq via
// readfirstlane-uniform pointer -> s_load; packed fp32 accumulation.
// ---------------------------------------------------------------------------
__global__ __launch_bounds__(256) void cart_kernel(
    const float* __restrict__ feats,
    const int*   __restrict__ layout,
    const float* __restrict__ mqg,      // (4096, 1296) Mq c-major
    float*       __restrict__ out)
{
  __shared__ float sX2T[144 * 65];               // 37440 B
  __shared__ int   sCol[64];
  __shared__ __align__(16) float sOut[4][576];   //  9216 B -> 46.9KB total
  const int tid  = threadIdx.x;
  const int wave = tid >> 6;
  const int lane = tid & 63;
  const int rwBase = blockIdx.x * 4;             // 4 row-blocks, same config

  if (tid < 64) sCol[tid] = layout[2 * ((size_t)rwBase * 64 + tid) + 1];
  __syncthreads();

  // stage X2 transposed: sX2T[c][j] = feats[col_j][c]
  #pragma unroll
  for (int k = 0; k < 9; ++k){
    int q = k * 256 + tid;                       // 0..2303 float4 tasks
    int j = q / 36, c4 = q - j * 36;
    const float4 xv = *(const float4*)(feats + (size_t)sCol[j] * 144 + c4 * 4);
    int c0 = c4 * 4;
    sX2T[(c0+0)*65 + j] = xv.x;
    sX2T[(c0+1)*65 + j] = xv.y;
    sX2T[(c0+2)*65 + j] = xv.z;
    sX2T[(c0+3)*65 + j] = xv.w;
  }
  __syncthreads();

  const int rw = __builtin_amdgcn_readfirstlane(rwBase + wave);
  const float* __restrict__ mq = mqg + (size_t)rw * MQ_STRIDE;  // SGPR-based

  float2 acc2[4];
  float acc8 = 0.f;
  #pragma unroll
  for (int k = 0; k < 4; ++k) acc2[k] = make_float2(0.f, 0.f);

  #pragma unroll 4
  for (int c = 0; c < 144; ++c){
    float x = sX2T[c * 65 + lane];
    float2 xx = make_float2(x, x);
    const float* mb = mq + c * 9;
    acc2[0] += xx * make_float2(mb[0], mb[1]);
    acc2[1] += xx * make_float2(mb[2], mb[3]);
    acc2[2] += xx * make_float2(mb[4], mb[5]);
    acc2[3] += xx * make_float2(mb[6], mb[7]);
    acc8 += x * mb[8];
  }

  // coalesced store via LDS staging (wave-local, no barrier needed)
  float* __restrict__ pO = sOut[wave];
  #pragma unroll
  for (int k = 0; k < 4; ++k){
    pO[lane * 9 + 2*k]     = acc2[k].x;
    pO[lane * 9 + 2*k + 1] = acc2[k].y;
  }
  pO[lane * 9 + 8] = acc8;
  float* __restrict__ ob = out + (size_t)rw * 576;
  #pragma unroll
  for (int r = 0; r < 3; ++r){
    int idx = lane + r * 64;                 // float4 index 0..143
    if (idx < 144){
      float4 vv = *(const float4*)(pO + idx * 4);
      *(float4*)(ob + idx * 4) = vv;
    }
  }
}

// ---------------------------------------------------------------------------
// fallback: fused LDS-broadcast kernel (used only if ws is too small)
// ---------------------------------------------------------------------------
__global__ __launch_bounds__(256, 4) void fused_kernel(
    const float* __restrict__ feats,
    const int*   __restrict__ layout,
    const float* __restrict__ tpw,
    float*       __restrict__ out)
{
  __shared__ __align__(16) float sB8[189 * 8];
  __shared__ float sB1[192];
  __shared__ __align__(16) float sT[4][816];
  __shared__ __align__(16) float sMqT[4][1296];
  const int tid  = threadIdx.x;
  const int wave = tid >> 6;
  const int lane = tid & 63;

  for (int o = tid; o < 1512; o += 256) sB8[o] = cWQ.b8[o];
  if (tid < 189) sB1[tid] = cWQ.b1[tid];

  const int rw = blockIdx.x * 4 + wave;
  const int e0 = rw * 64;
  int rowNode = layout[2 * e0];
  rowNode = __builtin_amdgcn_readfirstlane(rowNode);
  const float* __restrict__ x1 = feats + (size_t)rowNode * 144;

  float* __restrict__ pT = sT[wave];
  {
    const int v  = lane & 15;
    const int cq = lane >> 4;
    for (int it = 0; it < 13; ++it){
      int c = cq + it * 4;
      if (c < 51){
        int p = cC2P[c], i = cC2I[c];
        int l1 = cP_L1[p];
        int st = 2*l1 + 1;
        int loff = (l1 == 0) ? 0 : ((l1 == 1) ? 16 : 64);
        const float* xb = x1 + loff + i;
        const float* wb = tpw + p * 256 + v;
        float s = 0.f;
        #pragma unroll
        for (int u = 0; u < 16; ++u) s += xb[u * st] * wb[u * 16];
        pT[c * 16 + v] = s;
      }
    }
  }
  __syncthreads();

  float* __restrict__ pM = sMqT[wave];
  for (int rnd = 0; rnd < 3; ++rnd){
    int c = lane + rnd * 64;
    if (c >= 144) break;
    float2 acc2[4];
    float acc8 = 0.f;
    #pragma unroll
    for (int k = 0; k < 4; ++k) acc2[k] = make_float2(0.f, 0.f);
    if (c < 16){
      const int v = c, j = 0;
      const int D2 = 1;
      ACCP(0,  0,   1)
      ACCP(10, 38,  3)
      ACCP(30, 110, 5)
    } else if (c < 64){
      const int v = (c - 16) / 3, j = (c - 16) % 3;
      const int D2 = 3;
      ACCP(1,  1,   3)
      ACCP(9,  35,  1)
      ACCP(13, 41,  3)
      ACCP(19, 65,  5)
      ACCP(35, 115, 3)
      ACCP(41, 139, 5)
    } else {
      const int v = (c - 64) / 5, j = (c - 64) % 5;
      const int D2 = 5;
      ACCP(4,  10,  5)
      ACCP(16, 50,  3)
      ACCP(24, 80,  5)
      ACCP(29, 105, 1)
      ACCP(38, 124, 3)
      ACCP(46, 164, 5)
    }
    #pragma unroll
    for (int k = 0; k < 4; ++k){
      pM[(2*k) * 144 + c]     = acc2[k].x;
      pM[(2*k + 1) * 144 + c] = acc2[k].y;
    }
    pM[8 * 144 + c] = acc8;
  }

  const size_t e = (size_t)e0 + lane;
  const int col = layout[2 * e + 1];
  const float* __restrict__ x2 = feats + (size_t)col * 144;

  float acc[9];
  #pragma unroll
  for (int a = 0; a < 9; ++a) acc[a] = 0.f;

  for (int cc = 0; cc < 36; ++cc){
    const float4 x = *(const float4*)(x2 + cc * 4);
    const float* mb = pM + cc * 4;
    #pragma unroll
    for (int a = 0; a < 9; ++a){
      float4 mv = *(const float4*)(mb + a * 144);
      acc[a] += x.x*mv.x + x.y*mv.y + x.z*mv.z + x.w*mv.w;
    }
  }

  #pragma unroll
  for (int a = 0; a < 9; ++a) pT[lane * 9 + a] = acc[a];
  float* ob = out + (size_t)e0 * 9;
  #pragma unroll
  for (int r = 0; r < 3; ++r){
    int idx = lane + r * 64;
    if (idx < 144){
      float4 vv = *(const float4*)(pT + idx * 4);
      *(float4*)(ob + idx * 4) = vv;
    }
  }
}

// ---------------------------------------------------------------------------
// sym_tiled: 16x16 cell tile-pairs through LDS; fully coalesced; each element
// read+written exactly once. Block = (config b, tile-pair tp), 256 threads.
// ---------------------------------------------------------------------------
__global__ __launch_bounds__(256) void sym_tiled(float* __restrict__ out){
  __shared__ float sA[16 * 145];
  __shared__ float sB[16 * 145];
  const int tid = threadIdx.x;
  const int b  = blockIdx.x / 10;
  const int tp = blockIdx.x - b * 10;
  const int TI[10] = {0,0,0,0,1,1,1,2,2,3};
  const int TJ[10] = {0,1,2,3,1,2,3,2,3,3};
  const int ti = TI[tp], tj = TJ[tp];
  const bool diag = (ti == tj);
  const size_t cfgBase = (size_t)b * 4096 * 9;

  for (int idx = tid; idx < 2304; idx += 256){
    int r = idx / 144, off = idx - r * 144;
    sA[r * 145 + off] = out[cfgBase + ((size_t)(ti*16 + r) * 64 + tj*16) * 9 + off];
  }
  if (!diag){
    for (int idx = tid; idx < 2304; idx += 256){
      int r = idx / 144, off = idx - r * 144;
      sB[r * 145 + off] = out[cfgBase + ((size_t)(tj*16 + r) * 64 + ti*16) * 9 + off];
    }
  }
  __syncthreads();

  const int di = tid >> 4, dj = tid & 15;
  const float* A = sA;
  const float* B = diag ? sA : sB;
  float oa[9], ob[9];
  #pragma unroll
  for (int a = 0; a < 3; ++a)
    #pragma unroll
    for (int d = 0; d < 3; ++d){
      oa[a*3+d] = 0.5f * (A[di*145 + dj*9 + a*3+d] + B[dj*145 + di*9 + d*3+a]);
      if (!diag)
        ob[a*3+d] = 0.5f * (B[di*145 + dj*9 + a*3+d] + A[dj*145 + di*9 + d*3+a]);
    }
  __syncthreads();

  #pragma unroll
  for (int r9 = 0; r9 < 9; ++r9) sA[di*145 + dj*9 + r9] = oa[r9];
  if (!diag){
    #pragma unroll
    for (int r9 = 0; r9 < 9; ++r9) sB[di*145 + dj*9 + r9] = ob[r9];
  }
  __syncthreads();

  for (int idx = tid; idx < 2304; idx += 256){
    int r = idx / 144, off = idx - r * 144;
    out[cfgBase + ((size_t)(ti*16 + r) * 64 + tj*16) * 9 + off] = sA[r * 145 + off];
  }
  if (!diag){
    for (int idx = tid; idx < 2304; idx += 256){
      int r = idx / 144, off = idx - r * 144;
      out[cfgBase + ((size_t)(tj*16 + r) * 64 + ti*16) * 9 + off] = sB[r * 145 + off];
    }
  }
}

// ---------------------------------------------------------------------------
extern "C" void kernel_launch(void* const* d_in, const int* in_sizes, int n_in,
                              void* d_out, int out_size, void* d_ws, size_t ws_size,
                              hipStream_t stream) {
  const float* feats  = (const float*)d_in[0];   // (4096, 144)
  const int*   layout = (const int*)  d_in[1];   // (E, 2)
  const float* tpw    = (const float*)d_in[2];   // (15, 16, 16)
  float* out = (float*)d_out;
  float* ws  = (float*)d_ws;

  const int E = in_sizes[1] / 2;                 // 262144
  const int R = E / 64;                          // 4096 row-blocks
  const int B = E / 4096;                        // 64 configs

  const size_t need = (size_t)R * MQ_STRIDE * sizeof(float);
  if (ws_size >= need){
    float* mqg = ws;
    mq_kernel  <<<R / 4, 256, 0, stream>>>(feats, layout, tpw, mqg);
    cart_kernel<<<R / 4, 256, 0, stream>>>(feats, layout, mqg, out);
  } else {
    fused_kernel<<<R / 4, 256, 0, stream>>>(feats, layout, tpw, out);
  }
  sym_tiled<<<B * 10, 256, 0, stream>>>(out);
}

// Round 11
// 124.407 us; speedup vs baseline: 1.1155x; 1.0614x over previous
//
#include <hip/hip_runtime.h>
#include <math.h>

// ---------------------------------------------------------------------------
// IrrepsToHessian, round 11.
//
// R10 post-mortem: packed fp32 REGRESSED (+8us). v_pk_fma_f32 is VOP3P and
// needs VGPR operands; cart's Mq values live in SGPRs (s_load), so packing
// forced s->v moves. Scalar v_fmac folds one SGPR operand for free. Reverted.
//
// R11 = R8 exact structure (best measured, 124.3us) + one fix: cart's X2T
// staging re-indexed (j = q%64, c4 = q/64) so each ds_write instruction has
// fixed c and j == lane -> banks (c+j)%32 consecutive -> zero conflicts
// (R9/R10 measured 688K conflicts from the old order).
// ---------------------------------------------------------------------------

#define NPATH 15

// ======================= compile-time Wigner machinery =====================
constexpr double cfact(int n){ double r = 1.0; for (int i = 2; i <= n; ++i) r *= (double)i; return r; }
constexpr double csqrt(double x){
  if (x <= 0.0) return 0.0;
  double g = x < 1.0 ? 1.0 : x;
  for (int i = 0; i < 64; ++i) g = 0.5*(g + x/g);
  return g;
}

constexpr double ccg(int j1,int m1,int j2,int m2,int j3,int m3){
  if (m3 != m1 + m2) return 0.0;
  int vmin = -j1 + j2 + m3;
  if (-j1 + m1 > vmin) vmin = -j1 + m1;
  if (0 > vmin) vmin = 0;
  int vmax = j2 + j3 + m1;
  if (j3 - j1 + j2 < vmax) vmax = j3 - j1 + j2;
  if (j3 + m3 < vmax) vmax = j3 + m3;
  double C = csqrt((2.0*j3+1.0)*cfact(j3+j1-j2)*cfact(j3-j1+j2)*cfact(j1+j2-j3)
                   *cfact(j3+m3)*cfact(j3-m3)
                   /(cfact(j1+j2+j3+1)*cfact(j1-m1)*cfact(j1+m1)*cfact(j2-m2)*cfact(j2+m2)));
  double S = 0.0;
  for (int v = vmin; v <= vmax; ++v){
    double term = cfact(j2+j3+m1-v)*cfact(j1-m1+v)
                /(cfact(v)*cfact(j3-j1+j2-v)*cfact(j3+m3-v)*cfact(v+j1-j2-m3));
    S += ((v + j2 + m2) & 1) ? -term : term;
  }
  return C * S;
}

struct QM { double re[5][5]; double im[5][5]; };
constexpr QM cbuild_q(int l){
  QM q{};
  double s = 1.0 / csqrt(2.0);
  for (int m = -l; m < 0; ++m){
    q.re[l+m][l-m] = s;
    q.im[l+m][l+m] = -s;
  }
  q.re[l][l] = 1.0;
  for (int m = 1; m <= l; ++m){
    double sg = (m & 1) ? -1.0 : 1.0;
    q.re[l+m][l+m] = sg * s;
    q.im[l+m][l-m] = sg * s;
  }
  if (l == 1){           // * (-i): (a+bi) -> (b, -a)
    for (int r = 0; r < 5; ++r)
      for (int c = 0; c < 5; ++c){
        double a = q.re[r][c], b = q.im[r][c];
        q.re[r][c] = b; q.im[r][c] = -a;
      }
  } else if (l == 2){    // * (-1)
    for (int r = 0; r < 5; ++r)
      for (int c = 0; c < 5; ++c){ q.re[r][c] = -q.re[r][c]; q.im[r][c] = -q.im[r][c]; }
  }
  return q;
}

struct CRP { double v[125]; };   // normalized real w3j, [(i*d2+j)*d3+m]
constexpr CRP make_cr(int l1, int l2, int l3){
  QM q1 = cbuild_q(l1), q2 = cbuild_q(l2), q3 = cbuild_q(l3);
  const int d1 = 2*l1+1, d2 = 2*l2+1, d3 = 2*l3+1;
  double CG[125] = {};
  for (int i = 0; i < d1; ++i)
    for (int k = 0; k < d2; ++k)
      for (int m = 0; m < d3; ++m)
        CG[(i*5 + k)*5 + m] = ccg(l1, i-l1, l2, k-l2, l3, m-l3);
  CRP o{};
  for (int j = 0; j < d1; ++j)
    for (int l = 0; l < d2; ++l)
      for (int n = 0; n < d3; ++n){
        double acc = 0.0;
        for (int i = 0; i < d1; ++i)
          for (int k = 0; k < d2; ++k)
            for (int m = 0; m < d3; ++m){
              double c = CG[(i*5 + k)*5 + m];
              if (c == 0.0) continue;
              double are = q1.re[i][j], aim = q1.im[i][j];
              double bre = q2.re[k][l], bim = q2.im[k][l];
              double tre = are*bre - aim*bim;
              double tim = are*bim + aim*bre;
              double cre = q3.re[m][n], cim = q3.im[m][n];
              acc += (tre*cre + tim*cim) * c;   // Re( q1 q2 conj(q3) CG )
            }
        o.v[(j*d2 + l)*d3 + n] = acc;
      }
  double s2 = 0.0;
  for (int e = 0; e < d1*d2*d3; ++e) s2 += o.v[e]*o.v[e];
  double inv = 1.0 / csqrt(s2);
  for (int e = 0; e < d1*d2*d3; ++e) o.v[e] *= inv;
  return o;
}

// one constexpr variable per path -> each evaluation has its own step budget
constexpr CRP CR0  = make_cr(0,0,0);
constexpr CRP CR1  = make_cr(1,1,0);
constexpr CRP CR2  = make_cr(2,2,0);
constexpr CRP CR3  = make_cr(0,1,1);
constexpr CRP CR4  = make_cr(1,0,1);
constexpr CRP CR5  = make_cr(1,1,1);
constexpr CRP CR6  = make_cr(1,2,1);
constexpr CRP CR7  = make_cr(2,1,1);
constexpr CRP CR8  = make_cr(2,2,1);
constexpr CRP CR9  = make_cr(0,2,2);
constexpr CRP CR10 = make_cr(2,0,2);
constexpr CRP CR11 = make_cr(1,1,2);
constexpr CRP CR12 = make_cr(1,2,2);
constexpr CRP CR13 = make_cr(2,1,2);
constexpr CRP CR14 = make_cr(2,2,2);

struct QCT { double v[81]; };    // QCART[lm][i*3+j]
constexpr QCT make_qc(){
  QCT q{};
  for (int lm = 0; lm < 9; ++lm){
    int l = (lm == 0) ? 0 : ((lm < 4) ? 1 : 2);
    int m = lm - l*l;
    const CRP& cr = (l == 0) ? CR1 : ((l == 1) ? CR5 : CR11);  // paths (1,1,l)
    double sc = csqrt(2.0*l + 1.0);
    for (int r = 0; r < 9; ++r)
      q.v[lm*9 + r] = cr.v[r*(2*l+1) + m] * sc;
  }
  return q;
}
constexpr QCT QCt = make_qc();

// wq layout: 189 rows, split b8 (a<8) + b1 (a==8)
struct WQT { float b8[189*8]; float b1[189]; };
constexpr WQT make_wq(){
  WQT t{};
  const CRP* crs[NPATH] = {&CR0,&CR1,&CR2,&CR3,&CR4,&CR5,&CR6,&CR7,&CR8,&CR9,
                           &CR10,&CR11,&CR12,&CR13,&CR14};
  const int L1[NPATH]   = {0,1,2,0,1,1,1,2,2,0,2,1,1,2,2};
  const int L2[NPATH]   = {0,1,2,1,0,1,2,1,2,2,0,1,2,1,2};
  const int LO[NPATH]   = {0,0,0,1,1,1,1,1,1,2,2,2,2,2,2};
  const int PROW[NPATH] = {0,1,10,35,38,41,50,65,80,105,110,115,124,139,164};
  const double AL[3] = { csqrt(1.0/768.0), csqrt(3.0/1536.0), csqrt(5.0/1536.0) };
  for (int p = 0; p < NPATH; ++p){
    const int d1 = 2*L1[p]+1, d2 = 2*L2[p]+1, d3 = 2*LO[p]+1, lo = LO[p];
    for (int i = 0; i < d1; ++i)
      for (int j = 0; j < d2; ++j)
        for (int a = 0; a < 9; ++a){
          double acc = 0.0;
          for (int m = 0; m < d3; ++m)
            acc += crs[p]->v[(i*d2 + j)*d3 + m] * QCt.v[(lo*lo + m)*9 + a];
          double val = AL[lo] * acc;
          int row = PROW[p] + i*d2 + j;
          if (a < 8) t.b8[row*8 + a] = (float)val;
          else       t.b1[row]       = (float)val;
        }
  }
  return t;
}
__constant__ WQT cWQ = make_wq();

// ======================= runtime tables ====================================
__constant__ int cP_L1[NPATH]   = {0,1,2,0,1,1,1,2,2,0,2,1,1,2,2};
__constant__ int cC2P[51] = {0, 1,1,1, 2,2,2,2,2, 3, 4,4,4, 5,5,5, 6,6,6,
                             7,7,7,7,7, 8,8,8,8,8, 9, 10,10,10,10,10,
                             11,11,11, 12,12,12, 13,13,13,13,13, 14,14,14,14,14};
__constant__ int cC2I[51] = {0, 0,1,2, 0,1,2,3,4, 0, 0,1,2, 0,1,2, 0,1,2,
                             0,1,2,3,4, 0,1,2,3,4, 0, 0,1,2,3,4,
                             0,1,2, 0,1,2, 0,1,2,3,4, 0,1,2,3,4};

#define MQ_STRIDE 1296

// ACCP: one path's contribution to acc[9]
#define ACCP(TOFF_, PROW_, D1_)                                              \
  { _Pragma("unroll")                                                        \
    for (int i = 0; i < (D1_); ++i){                                         \
      float tv = pT[((TOFF_) + i) * 16 + v];                                 \
      int row = (PROW_) + i * D2 + j;                                        \
      const float4 m0 = *(const float4*)&sB8[row * 8];                       \
      const float4 m1 = *(const float4*)&sB8[row * 8 + 4];                   \
      const float  m8 = sB1[row];                                            \
      acc[0] += tv*m0.x; acc[1] += tv*m0.y; acc[2] += tv*m0.z;               \
      acc[3] += tv*m0.w; acc[4] += tv*m1.x; acc[5] += tv*m1.y;               \
      acc[6] += tv*m1.z; acc[7] += tv*m1.w; acc[8] += tv*m8;                 \
    } }

// ---------------------------------------------------------------------------
// mq_kernel: 256 thr = 4 waves; wave computes Mq (c-major [c][a]) for one
// row-block and stores it contiguously to global ws.
// ---------------------------------------------------------------------------
__global__ __launch_bounds__(256, 4) void mq_kernel(
    const float* __restrict__ feats,    // (4096, 144)
    const int*   __restrict__ layout,   // (E, 2)
    const float* __restrict__ tpw,      // (15, 16, 16)
    float*       __restrict__ mqg)      // (4096, 1296) Mq c-major
{
  __shared__ __align__(16) float sB8[189 * 8];      // 6048 B
  __shared__ float sB1[192];                        //  768 B
  __shared__ __align__(16) float sT[4][816];        // 13056 B
  __shared__ __align__(16) float sMq[4][1296];      // 20736 B -> 40.6KB total
  const int tid  = threadIdx.x;
  const int wave = tid >> 6;
  const int lane = tid & 63;

  for (int o = tid; o < 1512; o += 256) sB8[o] = cWQ.b8[o];
  if (tid < 189) sB1[tid] = cWQ.b1[tid];

  const int rw = blockIdx.x * 4 + wave;     // row-block id
  int rowNode = layout[2 * (rw * 64)];
  rowNode = __builtin_amdgcn_readfirstlane(rowNode);
  const float* __restrict__ x1 = feats + (size_t)rowNode * 144;

  // Phase A: t[k][v]
  float* __restrict__ pT = sT[wave];
  {
    const int v  = lane & 15;
    const int cq = lane >> 4;
    for (int it = 0; it < 13; ++it){
      int c = cq + it * 4;
      if (c < 51){
        int p = cC2P[c], i = cC2I[c];
        int l1 = cP_L1[p];
        int st = 2*l1 + 1;
        int loff = (l1 == 0) ? 0 : ((l1 == 1) ? 16 : 64);
        const float* xb = x1 + loff + i;
        const float* wb = tpw + p * 256 + v;
        float s = 0.f;
        #pragma unroll
        for (int u = 0; u < 16; ++u) s += xb[u * st] * wb[u * 16];
        pT[c * 16 + v] = s;
      }
    }
  }

  __syncthreads();   // sB8/sB1 staged; Phase A done

  // Phase B: Mq[c][a], c-major
  float* __restrict__ pM = sMq[wave];
  for (int rnd = 0; rnd < 3; ++rnd){
    int c = lane + rnd * 64;
    if (c >= 144) break;
    float acc[9];
    #pragma unroll
    for (int a = 0; a < 9; ++a) acc[a] = 0.f;
    if (c < 16){                    // l2 = 0 : paths 0,4,10
      const int v = c, j = 0;
      const int D2 = 1;
      ACCP(0,  0,   1)
      ACCP(10, 38,  3)
      ACCP(30, 110, 5)
    } else if (c < 64){             // l2 = 1 : paths 1,3,5,7,11,13
      const int v = (c - 16) / 3, j = (c - 16) % 3;
      const int D2 = 3;
      ACCP(1,  1,   3)
      ACCP(9,  35,  1)
      ACCP(13, 41,  3)
      ACCP(19, 65,  5)
      ACCP(35, 115, 3)
      ACCP(41, 139, 5)
    } else {                        // l2 = 2 : paths 2,6,8,9,12,14
      const int v = (c - 64) / 5, j = (c - 64) % 5;
      const int D2 = 5;
      ACCP(4,  10,  5)
      ACCP(16, 50,  3)
      ACCP(24, 80,  5)
      ACCP(29, 105, 1)
      ACCP(38, 124, 3)
      ACCP(46, 164, 5)
    }
    #pragma unroll
    for (int a = 0; a < 9; ++a) pM[c * 9 + a] = acc[a];
  }
  // wave-local LDS order: compiler's lgkmcnt before the reads below suffices

  // store Mq contiguously (coalesced b128)
  float* __restrict__ dst = mqg + (size_t)rw * MQ_STRIDE;
  #pragma unroll
  for (int r = 0; r < 6; ++r){
    int idx = lane + r * 64;                 // float4 index 0..323
    if (idx < 324){
      float4 vv = *(const float4*)(pM + idx * 4);
      *(float4*)(dst + idx * 4) = vv;
    }
  }
}

// ---------------------------------------------------------------------------
// cart_kernel: block = 4 row-blocks of ONE config (share the 64 columns).
// X2 staged transposed in LDS, conflict-free order (j = lane within each
// ds_write); Mq via readfirstlane-uniform pointer -> s_load SGPR-operand FMA.
// ---------------------------------------------------------------------------
__global__ __launch_bounds__(256) void cart_kernel(
    const float* __restrict__ feats,
    const int*   __restrict__ layout,
    const float* __restrict__ mqg,      // (4096, 1296) Mq c-major
    float*       __restrict__ out)
{
  __shared__ float sX2T[144 * 65];               // 37440 B
  __shared__ int   sCol[64];
  __shared__ __align__(16) float sOut[4][576];   //  9216 B -> 46.9KB total
  const int tid  = threadIdx.x;
  const int wave = tid >> 6;
  const int lane = tid & 63;
  const int rwBase = blockIdx.x * 4;             // 4 row-blocks, same config

  if (tid < 64) sCol[tid] = layout[2 * ((size_t)rwBase * 64 + tid) + 1];
  __syncthreads();

  // stage X2 transposed: sX2T[c][j] = feats[col_j][c]
  // task q: j = q%64 (== lane), c4 = q/64 -> per ds_write instruction c is
  // fixed and j==lane -> banks (c+j)%32 consecutive -> zero conflicts.
  #pragma unroll
  for (int k = 0; k < 9; ++k){
    int q = k * 256 + tid;                       // 0..2303 float4 tasks
    int j = q & 63, c4 = q >> 6;
    const float4 xv = *(const float4*)(feats + (size_t)sCol[j] * 144 + c4 * 4);
    int c0 = c4 * 4;
    sX2T[(c0+0)*65 + j] = xv.x;
    sX2T[(c0+1)*65 + j] = xv.y;
    sX2T[(c0+2)*65 + j] = xv.z;
    sX2T[(c0+3)*65 + j] = xv.w;
  }
  __syncthreads();

  const int rw = __builtin_amdgcn_readfirstlane(rwBase + wave);
  const float* __restrict__ mq = mqg + (size_t)rw * MQ_STRIDE;  // SGPR-based

  float acc[9];
  #pragma unroll
  for (int a = 0; a < 9; ++a) acc[a] = 0.f;

  #pragma unroll 8
  for (int c = 0; c < 144; ++c){
    float x = sX2T[c * 65 + lane];
    #pragma unroll
    for (int a = 0; a < 9; ++a) acc[a] += x * mq[c * 9 + a];
  }

  // coalesced store via LDS staging (wave-local, no barrier needed)
  float* __restrict__ pO = sOut[wave];
  #pragma unroll
  for (int a = 0; a < 9; ++a) pO[lane * 9 + a] = acc[a];
  float* __restrict__ ob = out + (size_t)rw * 576;
  #pragma unroll
  for (int r = 0; r < 3; ++r){
    int idx = lane + r * 64;                 // float4 index 0..143
    if (idx < 144){
      float4 vv = *(const float4*)(pO + idx * 4);
      *(float4*)(ob + idx * 4) = vv;
    }
  }
}

// ---------------------------------------------------------------------------
// fallback: fused LDS-broadcast kernel (used only if ws is too small)
// ---------------------------------------------------------------------------
__global__ __launch_bounds__(256, 4) void fused_kernel(
    const float* __restrict__ feats,
    const int*   __restrict__ layout,
    const float* __restrict__ tpw,
    float*       __restrict__ out)
{
  __shared__ __align__(16) float sB8[189 * 8];
  __shared__ float sB1[192];
  __shared__ __align__(16) float sT[4][816];
  __shared__ __align__(16) float sMqT[4][1296];
  const int tid  = threadIdx.x;
  const int wave = tid >> 6;
  const int lane = tid & 63;

  for (int o = tid; o < 1512; o += 256) sB8[o] = cWQ.b8[o];
  if (tid < 189) sB1[tid] = cWQ.b1[tid];

  const int rw = blockIdx.x * 4 + wave;
  const int e0 = rw * 64;
  int rowNode = layout[2 * e0];
  rowNode = __builtin_amdgcn_readfirstlane(rowNode);
  const float* __restrict__ x1 = feats + (size_t)rowNode * 144;

  float* __restrict__ pT = sT[wave];
  {
    const int v  = lane & 15;
    const int cq = lane >> 4;
    for (int it = 0; it < 13; ++it){
      int c = cq + it * 4;
      if (c < 51){
        int p = cC2P[c], i = cC2I[c];
        int l1 = cP_L1[p];
        int st = 2*l1 + 1;
        int loff = (l1 == 0) ? 0 : ((l1 == 1) ? 16 : 64);
        const float* xb = x1 + loff + i;
        const float* wb = tpw + p * 256 + v;
        float s = 0.f;
        #pragma unroll
        for (int u = 0; u < 16; ++u) s += xb[u * st] * wb[u * 16];
        pT[c * 16 + v] = s;
      }
    }
  }
  __syncthreads();

  float* __restrict__ pM = sMqT[wave];
  for (int rnd = 0; rnd < 3; ++rnd){
    int c = lane + rnd * 64;
    if (c >= 144) break;
    float acc[9];
    #pragma unroll
    for (int a = 0; a < 9; ++a) acc[a] = 0.f;
    if (c < 16){
      const int v = c, j = 0;
      const int D2 = 1;
      ACCP(0,  0,   1)
      ACCP(10, 38,  3)
      ACCP(30, 110, 5)
    } else if (c < 64){
      const int v = (c - 16) / 3, j = (c - 16) % 3;
      const int D2 = 3;
      ACCP(1,  1,   3)
      ACCP(9,  35,  1)
      ACCP(13, 41,  3)
      ACCP(19, 65,  5)
      ACCP(35, 115, 3)
      ACCP(41, 139, 5)
    } else {
      const int v = (c - 64) / 5, j = (c - 64) % 5;
      const int D2 = 5;
      ACCP(4,  10,  5)
      ACCP(16, 50,  3)
      ACCP(24, 80,  5)
      ACCP(29, 105, 1)
      ACCP(38, 124, 3)
      ACCP(46, 164, 5)
    }
    #pragma unroll
    for (int a = 0; a < 9; ++a) pM[a * 144 + c] = acc[a];
  }

  const size_t e = (size_t)e0 + lane;
  const int col = layout[2 * e + 1];
  const float* __restrict__ x2 = feats + (size_t)col * 144;

  float acc[9];
  #pragma unroll
  for (int a = 0; a < 9; ++a) acc[a] = 0.f;

  for (int cc = 0; cc < 36; ++cc){
    const float4 x = *(const float4*)(x2 + cc * 4);
    const float* mb = pM + cc * 4;
    #pragma unroll
    for (int a = 0; a < 9; ++a){
      float4 mv = *(const float4*)(mb + a * 144);
      acc[a] += x.x*mv.x + x.y*mv.y + x.z*mv.z + x.w*mv.w;
    }
  }

  #pragma unroll
  for (int a = 0; a < 9; ++a) pT[lane * 9 + a] = acc[a];
  float* ob = out + (size_t)e0 * 9;
  #pragma unroll
  for (int r = 0; r < 3; ++r){
    int idx = lane + r * 64;
    if (idx < 144){
      float4 vv = *(const float4*)(pT + idx * 4);
      *(float4*)(ob + idx * 4) = vv;
    }
  }
}

// ---------------------------------------------------------------------------
// sym_tiled: 16x16 cell tile-pairs through LDS; fully coalesced; each element
// read+written exactly once. Block = (config b, tile-pair tp), 256 threads.
// ---------------------------------------------------------------------------
__global__ __launch_bounds__(256) void sym_tiled(float* __restrict__ out){
  __shared__ float sA[16 * 145];
  __shared__ float sB[16 * 145];
  const int tid = threadIdx.x;
  const int b  = blockIdx.x / 10;
  const int tp = blockIdx.x - b * 10;
  const int TI[10] = {0,0,0,0,1,1,1,2,2,3};
  const int TJ[10] = {0,1,2,3,1,2,3,2,3,3};
  const int ti = TI[tp], tj = TJ[tp];
  const bool diag = (ti == tj);
  const size_t cfgBase = (size_t)b * 4096 * 9;

  for (int idx = tid; idx < 2304; idx += 256){
    int r = idx / 144, off = idx - r * 144;
    sA[r * 145 + off] = out[cfgBase + ((size_t)(ti*16 + r) * 64 + tj*16) * 9 + off];
  }
  if (!diag){
    for (int idx = tid; idx < 2304; idx += 256){
      int r = idx / 144, off = idx - r * 144;
      sB[r * 145 + off] = out[cfgBase + ((size_t)(tj*16 + r) * 64 + ti*16) * 9 + off];
    }
  }
  __syncthreads();

  const int di = tid >> 4, dj = tid & 15;
  const float* A = sA;
  const float* B = diag ? sA : sB;
  float oa[9], ob[9];
  #pragma unroll
  for (int a = 0; a < 3; ++a)
    #pragma unroll
    for (int d = 0; d < 3; ++d){
      oa[a*3+d] = 0.5f * (A[di*145 + dj*9 + a*3+d] + B[dj*145 + di*9 + d*3+a]);
      if (!diag)
        ob[a*3+d] = 0.5f * (B[di*145 + dj*9 + a*3+d] + A[dj*145 + di*9 + d*3+a]);
    }
  __syncthreads();

  #pragma unroll
  for (int r9 = 0; r9 < 9; ++r9) sA[di*145 + dj*9 + r9] = oa[r9];
  if (!diag){
    #pragma unroll
    for (int r9 = 0; r9 < 9; ++r9) sB[di*145 + dj*9 + r9] = ob[r9];
  }
  __syncthreads();

  for (int idx = tid; idx < 2304; idx += 256){
    int r = idx / 144, off = idx - r * 144;
    out[cfgBase + ((size_t)(ti*16 + r) * 64 + tj*16) * 9 + off] = sA[r * 145 + off];
  }
  if (!diag){
    for (int idx = tid; idx < 2304; idx += 256){
      int r = idx / 144, off = idx - r * 144;
      out[cfgBase + ((size_t)(tj*16 + r) * 64 + ti*16) * 9 + off] = sB[r * 145 + off];
    }
  }
}

// ---------------------------------------------------------------------------
extern "C" void kernel_launch(void* const* d_in, const int* in_sizes, int n_in,
                              void* d_out, int out_size, void* d_ws, size_t ws_size,
                              hipStream_t stream) {
  const float* feats  = (const float*)d_in[0];   // (4096, 144)
  const int*   layout = (const int*)  d_in[1];   // (E, 2)
  const float* tpw    = (const float*)d_in[2];   // (15, 16, 16)
  float* out = (float*)d_out;
  float* ws  = (float*)d_ws;

  const int E = in_sizes[1] / 2;                 // 262144
  const int R = E / 64;                          // 4096 row-blocks
  const int B = E / 4096;                        // 64 configs

  const size_t need = (size_t)R * MQ_STRIDE * sizeof(float);
  if (ws_size >= need){
    float* mqg = ws;
    mq_kernel  <<<R / 4, 256, 0, stream>>>(feats, layout, tpw, mqg);
    cart_kernel<<<R / 4, 256, 0, stream>>>(feats, layout, mqg, out);
  } else {
    fused_kernel<<<R / 4, 256, 0, stream>>>(feats, layout, tpw, out);
  }
  sym_tiled<<<B * 10, 256, 0, stream>>>(out);
}